// Round 7
// baseline (98.689 us; speedup 1.0000x reference)
//
#include <hip/hip_runtime.h>

#define ORDER 8
#define FDIM 4096
#define NROWS 8192
#define THREADS 256
#define F4T 4            // fvec4 chunks per thread (prep/gram): 4096/4/256
#define F4DIM (FDIM/4)   // 1024 fvec4 per row
#define NPAIR 36         // upper-triangular pairs of 8
#define RPW 2            // rows per wave (main kernel)

typedef float fvec4 __attribute__((ext_vector_type(4)));

// ---------------------------------------------------------------------------
// Prep: reparameterize v, d, bias; normalize v rows.
// blocks 0..7 -> vn row b ; block 8 -> d ; block 9 -> bias
// ---------------------------------------------------------------------------
__global__ __launch_bounds__(THREADS) void obd_prep(
    const float* __restrict__ v_mean, const float* __restrict__ v_logvar,
    const float* __restrict__ eps_v,
    const float* __restrict__ d_mean, const float* __restrict__ d_logvar,
    const float* __restrict__ eps_d,
    const float* __restrict__ b_mean, const float* __restrict__ b_logvar,
    const float* __restrict__ eps_b,
    float* __restrict__ vn, float* __restrict__ dsc, float* __restrict__ bias)
{
    const int b = blockIdx.x;
    const int t = threadIdx.x;
    __shared__ float red[THREADS / 64];

    if (b < ORDER) {
        const fvec4* vm = (const fvec4*)(v_mean   + (size_t)b * FDIM);
        const fvec4* vl = (const fvec4*)(v_logvar + (size_t)b * FDIM);
        const fvec4* ev = (const fvec4*)(eps_v    + (size_t)b * FDIM);
        fvec4 val[F4T];
        float ss = 0.f;
        #pragma unroll
        for (int k = 0; k < F4T; ++k) {
            const int idx = t + k * THREADS;
            fvec4 m = vm[idx], l = vl[idx], e = ev[idx];
            fvec4 v;
            #pragma unroll
            for (int c = 0; c < 4; ++c)
                v[c] = fmaf(expf(0.5f * l[c]), e[c], m[c]);
            val[k] = v;
            ss += v[0]*v[0] + v[1]*v[1] + v[2]*v[2] + v[3]*v[3];
        }
        #pragma unroll
        for (int off = 32; off; off >>= 1) ss += __shfl_down(ss, off);
        const int wave = t >> 6, lane = t & 63;
        if (lane == 0) red[wave] = ss;
        __syncthreads();
        const float inv = 1.0f / sqrtf(red[0] + red[1] + red[2] + red[3]);
        fvec4* vno = (fvec4*)(vn + (size_t)b * FDIM);
        #pragma unroll
        for (int k = 0; k < F4T; ++k)
            vno[t + k * THREADS] = val[k] * inv;
    } else if (b == ORDER) {
        #pragma unroll
        for (int k = 0; k < 16; ++k) {
            const int idx = t + k * THREADS;
            dsc[idx] = fmaf(expf(0.5f * d_logvar[idx]), eps_d[idx], d_mean[idx]);
        }
    } else {
        #pragma unroll
        for (int k = 0; k < 16; ++k) {
            const int idx = t + k * THREADS;
            bias[idx] = fmaf(expf(0.5f * b_logvar[idx]), eps_b[idx], b_mean[idx]);
        }
    }
}

// ---------------------------------------------------------------------------
// Gram + T + Md: single block.
//   G[i][j] = vn_i . vn_j  (block reduce)
//   T: compact-WY factor (thread 0): H0..H7 = I - V^T T V
//   Md[i][c] = -(T V)[i][c] * d[c]   -> rank-8 update matrix for obd_main
// ---------------------------------------------------------------------------
__global__ __launch_bounds__(THREADS) void obd_gramT(
    const float* __restrict__ vn, const float* __restrict__ dsc,
    float* __restrict__ Md)
{
    const int t = threadIdx.x;
    const int wave = t >> 6, lane = t & 63;
    const fvec4* Vv = (const fvec4*)vn;

    float acc[ORDER][ORDER];
    #pragma unroll
    for (int i = 0; i < ORDER; ++i)
        #pragma unroll
        for (int j = i; j < ORDER; ++j) acc[i][j] = 0.f;

    #pragma unroll
    for (int k = 0; k < F4T; ++k) {
        const int idx = t + k * THREADS;
        fvec4 vc[ORDER];
        #pragma unroll
        for (int i = 0; i < ORDER; ++i) vc[i] = Vv[i * F4DIM + idx];
        #pragma unroll
        for (int i = 0; i < ORDER; ++i)
            #pragma unroll
            for (int j = i; j < ORDER; ++j)
                #pragma unroll
                for (int c = 0; c < 4; ++c)
                    acc[i][j] = fmaf(vc[i][c], vc[j][c], acc[i][j]);
    }
    #pragma unroll
    for (int off = 32; off; off >>= 1)
        #pragma unroll
        for (int i = 0; i < ORDER; ++i)
            #pragma unroll
            for (int j = i; j < ORDER; ++j)
                acc[i][j] += __shfl_down(acc[i][j], off);

    __shared__ float red[THREADS / 64][NPAIR];
    __shared__ float Tsh[ORDER * ORDER];
    if (lane == 0) {
        int p = 0;
        #pragma unroll
        for (int i = 0; i < ORDER; ++i)
            #pragma unroll
            for (int j = i; j < ORDER; ++j) red[wave][p++] = acc[i][j];
    }
    __syncthreads();
    if (t == 0) {
        float G[ORDER][ORDER];
        int p = 0;
        for (int i = 0; i < ORDER; ++i)
            for (int j = i; j < ORDER; ++j) {
                G[i][j] = red[0][p] + red[1][p] + red[2][p] + red[3][p];
                ++p;
            }
        float T[ORDER][ORDER];
        for (int i = 0; i < ORDER; ++i)
            for (int j = 0; j < ORDER; ++j) T[i][j] = 0.f;
        T[0][0] = 2.f;
        for (int j = 1; j < ORDER; ++j) {
            for (int i = 0; i < j; ++i) {
                float s = 0.f;
                for (int m = i; m < j; ++m) s += T[i][m] * G[m][j];
                T[i][j] = -2.f * s;
            }
            T[j][j] = 2.f;
        }
        for (int i = 0; i < ORDER; ++i)
            for (int j = 0; j < ORDER; ++j) Tsh[i * ORDER + j] = T[i][j];
    }
    __syncthreads();

    // Md[i][c] = -(sum_{m>=i} T[i][m] * V[m][c]) * d[c]
    const fvec4* dv = (const fvec4*)dsc;
    fvec4* Mdv = (fvec4*)Md;
    #pragma unroll
    for (int k = 0; k < F4T; ++k) {
        const int idx = t + k * THREADS;
        fvec4 vcol[ORDER];
        #pragma unroll
        for (int m = 0; m < ORDER; ++m) vcol[m] = Vv[m * F4DIM + idx];
        const fvec4 dd = dv[idx];
        #pragma unroll
        for (int i = 0; i < ORDER; ++i) {
            fvec4 s = {0.f, 0.f, 0.f, 0.f};
            #pragma unroll
            for (int m = 0; m < ORDER; ++m) {
                if (m >= i) {
                    const float tv = Tsh[i * ORDER + m];
                    #pragma unroll
                    for (int c = 0; c < 4; ++c) s[c] = fmaf(tv, vcol[m][c], s[c]);
                }
            }
            Mdv[i * F4DIM + idx] = -(s * dd);
        }
    }
}

// ---------------------------------------------------------------------------
// Main (fused, barrier-free): each wave owns RPW=2 rows end-to-end.
//   sweep 1: p[rr][i] = row . v_i  (x from HBM/L3, vn from L2)
//   xor-butterfly: ALL 64 lanes end with the complete dots (no LDS needed)
//   sweep 2: out = x*d + sum_i p[i]*Md[i] + bias  (x re-read L2/L3-hot,
//            Md from L2, nontemporal store)
// No __syncthreads, no LDS, no P round-trip, waves fully independent.
// launch_bounds(256,2): VGPR cap 128 (live ~70, no spill — R5 showed the
// compiler balloons past 128 if uncapped, killing occupancy).
// ---------------------------------------------------------------------------
__global__ __launch_bounds__(THREADS, 2) void obd_main(
    const float* __restrict__ x, const float* __restrict__ vn,
    const float* __restrict__ Md, const float* __restrict__ dsc,
    const float* __restrict__ bias, float* __restrict__ out)
{
    const int t = threadIdx.x;
    const int wave = t >> 6, lane = t & 63;
    const size_t r0 = ((size_t)blockIdx.x * 4 + wave) * RPW;
    const fvec4* xv = (const fvec4*)x;
    const fvec4* Vv = (const fvec4*)vn;

    // Sweep 1: dots.
    float p[RPW][ORDER];
    #pragma unroll
    for (int rr = 0; rr < RPW; ++rr)
        #pragma unroll
        for (int i = 0; i < ORDER; ++i) p[rr][i] = 0.f;

    #pragma unroll 4
    for (int it = 0; it < F4DIM / 64; ++it) {
        const int idx = it * 64 + lane;
        fvec4 xr[RPW];
        #pragma unroll
        for (int rr = 0; rr < RPW; ++rr)
            xr[rr] = xv[(r0 + rr) * F4DIM + idx];
        #pragma unroll
        for (int i = 0; i < ORDER; ++i) {
            const fvec4 vc = Vv[i * F4DIM + idx];
            #pragma unroll
            for (int rr = 0; rr < RPW; ++rr)
                #pragma unroll
                for (int c = 0; c < 4; ++c)
                    p[rr][i] = fmaf(xr[rr][c], vc[c], p[rr][i]);
        }
    }

    // Full butterfly: every lane gets the complete dot values.
    #pragma unroll
    for (int off = 32; off; off >>= 1)
        #pragma unroll
        for (int rr = 0; rr < RPW; ++rr)
            #pragma unroll
            for (int i = 0; i < ORDER; ++i)
                p[rr][i] += __shfl_xor(p[rr][i], off);

    // Sweep 2: combine + store.
    const fvec4* Mdv = (const fvec4*)Md;
    const fvec4* dv  = (const fvec4*)dsc;
    const fvec4* bv  = (const fvec4*)bias;
    fvec4* ov        = (fvec4*)out;

    #pragma unroll 4
    for (int it = 0; it < F4DIM / 64; ++it) {
        const int idx = it * 64 + lane;
        const fvec4 dd = dv[idx];
        const fvec4 bb = bv[idx];
        fvec4 acc[RPW];
        #pragma unroll
        for (int rr = 0; rr < RPW; ++rr) {
            const fvec4 xr = xv[(r0 + rr) * F4DIM + idx];
            #pragma unroll
            for (int c = 0; c < 4; ++c)
                acc[rr][c] = fmaf(xr[c], dd[c], bb[c]);
        }
        #pragma unroll
        for (int i = 0; i < ORDER; ++i) {
            const fvec4 md = Mdv[i * F4DIM + idx];
            #pragma unroll
            for (int rr = 0; rr < RPW; ++rr)
                #pragma unroll
                for (int c = 0; c < 4; ++c)
                    acc[rr][c] = fmaf(p[rr][i], md[c], acc[rr][c]);
        }
        #pragma unroll
        for (int rr = 0; rr < RPW; ++rr)
            __builtin_nontemporal_store(acc[rr], &ov[(r0 + rr) * F4DIM + idx]);
    }
}

extern "C" void kernel_launch(void* const* d_in, const int* in_sizes, int n_in,
                              void* d_out, int out_size, void* d_ws, size_t ws_size,
                              hipStream_t stream) {
    const float* x        = (const float*)d_in[0];
    const float* v_mean   = (const float*)d_in[1];
    const float* v_logvar = (const float*)d_in[2];
    const float* d_mean   = (const float*)d_in[3];
    const float* d_logvar = (const float*)d_in[4];
    const float* b_mean   = (const float*)d_in[5];
    const float* b_logvar = (const float*)d_in[6];
    const float* eps_v    = (const float*)d_in[7];
    const float* eps_d    = (const float*)d_in[8];
    const float* eps_b    = (const float*)d_in[9];

    float* ws   = (float*)d_ws;
    float* vn   = ws;                        // 8*4096
    float* dsc  = vn + ORDER * FDIM;         // 4096
    float* bias = dsc + FDIM;                // 4096
    float* Md   = bias + FDIM;               // 8*4096

    obd_prep<<<ORDER + 2, THREADS, 0, stream>>>(
        v_mean, v_logvar, eps_v, d_mean, d_logvar, eps_d,
        b_mean, b_logvar, eps_b, vn, dsc, bias);
    obd_gramT<<<1, THREADS, 0, stream>>>(vn, dsc, Md);
    obd_main<<<NROWS / (4 * RPW), THREADS, 0, stream>>>(
        x, vn, Md, dsc, bias, (float*)d_out);
}